// Round 8
// baseline (481.266 us; speedup 1.0000x reference)
//
#include <hip/hip_runtime.h>
#include <stdint.h>

#define P 2048
#define R 65536
#define DD 512
#define BM 256
#define BN 256
#define BK 64
#define NT (DD / BK)   // 8 K-tiles

typedef __attribute__((ext_vector_type(8))) short short8;
typedef __attribute__((ext_vector_type(4))) float f32x4;

__device__ inline unsigned short f2bf(float f) {
  unsigned int u = __float_as_uint(f);
  u += 0x7fffu + ((u >> 16) & 1u);   // round-to-nearest-even
  return (unsigned short)(u >> 16);
}

__device__ inline void gload_lds16(const void* g, void* l) {
  __builtin_amdgcn_global_load_lds(
      (const __attribute__((address_space(1))) unsigned int*)g,
      (__attribute__((address_space(3))) unsigned int*)l,
      16, 0, 0);
}

// ---- kernel 1: fp32 -> bf16 conversion + fp32 row norms; one wave per row,
//      grid-stride. pred rows -> Abf row-major (for LDS staging). cand rows ->
//      Bpk in PACKED MFMA-FRAGMENT ORDER: Bpk[nb][c][j][lane] (16B units),
//      nb=row>>6 (64-col n-block), c=k>>5 (32-wide k-chunk), j=(row>>4)&3,
//      lane = quad*16 + (row&15) with quad=(k>>3)&3. A gemm wave's B-frag
//      load is then ONE coalesced 1KB global_load_dwordx4 -> B never touches
//      LDS. Convert lane L holds k=8L..8L+7 = exactly piece (c=L>>2, q=L&3).
__global__ __launch_bounds__(256) void k_convert(
    const float* __restrict__ pred, const float* __restrict__ cand,
    unsigned short* __restrict__ Abf, unsigned short* __restrict__ Bpk,
    float* __restrict__ nx, float* __restrict__ ny,
    unsigned int* __restrict__ minp)
{
  if (blockIdx.x == 0 && threadIdx.x == 0) *minp = 0x7f800000u; // +inf bits
  const int lane = threadIdx.x & 63;
  const int wv   = (blockIdx.x << 2) | (threadIdx.x >> 6);
  const int nw   = gridDim.x << 2;
  for (int gw = wv; gw < P + R; gw += nw) {
    const float* src; float* np;
    if (gw < P) { src = pred + (size_t)gw * DD; np = nx + gw; }
    else        { src = cand + (size_t)(gw - P) * DD; np = ny + (gw - P); }
    const float4* s4 = ((const float4*)src) + lane * 2;
    float4 v0 = s4[0], v1 = s4[1];
    float ss = v0.x*v0.x + v0.y*v0.y + v0.z*v0.z + v0.w*v0.w
             + v1.x*v1.x + v1.y*v1.y + v1.z*v1.z + v1.w*v1.w;
    union { unsigned short h[8]; uint4 v; } pk;
    pk.h[0]=f2bf(v0.x); pk.h[1]=f2bf(v0.y); pk.h[2]=f2bf(v0.z); pk.h[3]=f2bf(v0.w);
    pk.h[4]=f2bf(v1.x); pk.h[5]=f2bf(v1.y); pk.h[6]=f2bf(v1.z); pk.h[7]=f2bf(v1.w);
    if (gw < P) {
      *(uint4*)(Abf + (size_t)gw * DD + lane * 8) = pk.v;
    } else {
      const int r = gw - P;
      const size_t off = (((size_t)(r >> 6) * 16 + (lane >> 2)) * 4 + ((r >> 4) & 3)) * 512
                       + (size_t)((lane & 3) * 16 + (r & 15)) * 8;
      *(uint4*)(Bpk + off) = pk.v;
    }
    #pragma unroll
    for (int off = 32; off; off >>= 1) ss += __shfl_down(ss, off, 64);
    if (lane == 0) *np = ss;
  }
}

// ---- kernel 2: 256x256 bf16 MFMA GEMM (A·B^T), BK=64, 8 waves (2Mx4N),
//      *** B DIRECT-FROM-GLOBAL (packed fragment order, register double-
//      buffered, async via counted vmcnt) — B never enters LDS. A in LDS,
//      double-buffered, round-1 measured-zero-conflict chunk-XOR swizzle.
//      SINGLE barrier per tile, no vmcnt(0) drain in the main loop. ***
//      LDS read traffic: 24 -> 16 b128/wave/tile; stage writes halved.
//
// Per-tile T (A buf s=T&1, B regs cur/nxt ping-pong):
//   STAGE_A(s^1, T+1)  [4 gload_lds]      \ issued before compute; pinned by
//   LOADB(nxt, T+1)    [8 coalesced b128] /  sched_barrier
//   COMPUTE(s, cur)    [16 ds_read_b128 + 64 MFMA; compiler inserts counted
//                       lgkm waits for A-frags and counted vmcnt for cur]
//   sched_barrier; s_waitcnt vmcnt(8)  [drains A(T+1) (4 oldest of 12);
//                                       B(T+1) keeps flying]
//   s_barrier                          [As[s^1] ready for everyone]
// B(T) landed-check is compiler-inserted (tracked reg dependence), counted,
// and B was issued a full tile (~4000cy >> 900cy latency) ahead.
__global__ __launch_bounds__(512, 2) void k_gemm_min(
    const unsigned short* __restrict__ Abf, const unsigned short* __restrict__ Bpk,
    const float* __restrict__ nx, const float* __restrict__ ny,
    unsigned int* __restrict__ minp)
{
  __shared__ __align__(16) unsigned short As[2][BM * BK];   // 2 x 32 KB
  __shared__ float wmin[8];

  const int tid  = threadIdx.x;
  const int wave = tid >> 6;          // 0..7
  const int lane = tid & 63;

  // XCD-aware bijective remap: 2048 blocks, 8 XCDs, 256 contiguous per XCD.
  // by fast -> 8 adjacent wg (one bx) run on the same XCD: Bpk chunk L2-hits.
  const int raw = blockIdx.x;
  const int wg  = (raw & 7) * 256 + (raw >> 3);
  const int by  = wg & 7;
  const int bx  = wg >> 3;
  const int rowA0 = by * BM, rowB0 = bx * BN;
  const int wr = wave >> 2;           // 0..1 : M half   (wave tile 128x64)
  const int wc = wave & 3;            // 0..3 : N quarter

  f32x4 zero = {0.f, 0.f, 0.f, 0.f};
  f32x4 acc[8][4];
  #pragma unroll
  for (int i = 0; i < 8; ++i)
    #pragma unroll
    for (int j = 0; j < 4; ++j) acc[i][j] = zero;

  // A staging: 32 wave-instrs (8 waves x t=0..3), each 8 rows x 64 cols (1KB).
  // lane L -> local row L>>3, stored chunk L&7, source data chunk (L&7)^(L>>3).
  const int rloc = lane >> 3;
  const int cswz = (lane & 7) ^ rloc;
  const unsigned short* gA[4];
  int lofs[4];
  #pragma unroll
  for (int t = 0; t < 4; ++t) {
    const int ii = wave * 4 + t;          // 0..31
    gA[t] = Abf + (size_t)(rowA0 + ii * 8 + rloc) * DD + cswz * 8;
    lofs[t] = ii * 512;
  }

#define STAGE_A(s, kt) do { const int _k0 = (kt) * BK;          \
    _Pragma("unroll")                                           \
    for (int _t = 0; _t < 4; ++_t)                              \
      gload_lds16(gA[_t] + _k0, &As[s][lofs[_t]]);              \
  } while (0)

  // B fragment pointers: unit (nb, c, j) = 512 shorts; wave's nb = bx*4+wc.
  const unsigned short* bbase = Bpk + (size_t)(bx * 4 + wc) * 64 * 512 + lane * 8;

#define LOADB(dst, T) do {                                                    \
    _Pragma("unroll")                                                         \
    for (int _h = 0; _h < 2; ++_h)                                            \
      _Pragma("unroll")                                                       \
      for (int _j = 0; _j < 4; ++_j)                                          \
        dst[_j][_h] = *(const short8*)(bbase +                                \
            (size_t)((2 * (T) + _h) * 4 + _j) * 512);                         \
  } while (0)

  // A fragment read geometry (16x16x32, round-1 proven conflict-free):
  // frag row = wr*128 + (mh*4+i)*16 + m; k-chunk (h*4+quad) stored ^ (m&7).
  const int m = lane & 15, quad = lane >> 4, mb = m & 7;
  const int aRow0 = (wr * 128 + m) * BK;
  const int sw0 = ((quad    ) ^ mb) * 8;
  const int sw1 = ((quad + 4) ^ mb) * 8;

#define COMPUTE(s, bcur) do {                                                 \
    _Pragma("unroll")                                                         \
    for (int _mh = 0; _mh < 2; ++_mh)                                         \
      _Pragma("unroll")                                                       \
      for (int _h = 0; _h < 2; ++_h) {                                        \
        short8 _af[4];                                                        \
        const int _sw = _h ? sw1 : sw0;                                       \
        _Pragma("unroll")                                                     \
        for (int _i = 0; _i < 4; ++_i)                                        \
          _af[_i] = *(const short8*)(&As[s][aRow0 + (_mh*4+_i)*16*BK + _sw]); \
        __builtin_amdgcn_s_setprio(1);                                        \
        _Pragma("unroll")                                                     \
        for (int _i = 0; _i < 4; ++_i)                                        \
          _Pragma("unroll")                                                   \
          for (int _j = 0; _j < 4; ++_j)                                      \
            acc[_mh*4+_i][_j] = __builtin_amdgcn_mfma_f32_16x16x32_bf16(      \
                _af[_i], bcur[_j][_h], acc[_mh*4+_i][_j], 0, 0, 0);           \
        __builtin_amdgcn_s_setprio(0);                                        \
      }                                                                       \
  } while (0)

  short8 bA[4][2], bB[4][2];

  // prologue: tile 0 (A issued before B so vmcnt(8) drains exactly A)
  STAGE_A(0, 0);
  LOADB(bA, 0);
  __builtin_amdgcn_sched_barrier(0);
  asm volatile("s_waitcnt vmcnt(8)" ::: "memory");   // A(0) landed
  __builtin_amdgcn_s_barrier();

  #pragma unroll 1
  for (int T = 0; T < NT; T += 2) {
    // even phase: A buf 0, B regs bA
    if (T + 1 < NT) { STAGE_A(1, T + 1); LOADB(bB, T + 1); }
    __builtin_amdgcn_sched_barrier(0);   // pin issues above compute
    COMPUTE(0, bA);
    __builtin_amdgcn_sched_barrier(0);
    asm volatile("s_waitcnt vmcnt(8)" ::: "memory"); // A(T+1) landed, B flies
    __builtin_amdgcn_s_barrier();

    // odd phase: A buf 1, B regs bB
    if (T + 1 < NT) {
      if (T + 2 < NT) { STAGE_A(0, T + 2); LOADB(bA, T + 2); }
      __builtin_amdgcn_sched_barrier(0);
      COMPUTE(1, bB);
      __builtin_amdgcn_sched_barrier(0);
      asm volatile("s_waitcnt vmcnt(8)" ::: "memory");
      __builtin_amdgcn_s_barrier();
    }
  }
#undef STAGE_A
#undef LOADB
#undef COMPUTE

  // epilogue: d^2 = ||x||^2 + ||y||^2 - 2*dot ; C/D layout col=lane&15, row=quad*4+reg
  float lmin = 3.4e38f;
  #pragma unroll
  for (int i = 0; i < 8; ++i) {
    const int mbase = rowA0 + wr * 128 + i * 16 + quad * 4;
    float4 nxv = *(const float4*)(nx + mbase);
    #pragma unroll
    for (int j = 0; j < 4; ++j) {
      const int n = rowB0 + wc * 64 + j * 16 + m;
      const float nyv = ny[n];
      f32x4 a = acc[i][j];
      lmin = fminf(lmin, nxv.x + nyv - 2.0f * a[0]);
      lmin = fminf(lmin, nxv.y + nyv - 2.0f * a[1]);
      lmin = fminf(lmin, nxv.z + nyv - 2.0f * a[2]);
      lmin = fminf(lmin, nxv.w + nyv - 2.0f * a[3]);
    }
  }
  #pragma unroll
  for (int off = 32; off; off >>= 1) lmin = fminf(lmin, __shfl_down(lmin, off, 64));
  if (lane == 0) wmin[wave] = lmin;
  __syncthreads();
  if (tid == 0) {
    float mn = wmin[0];
    #pragma unroll
    for (int w = 1; w < 8; ++w) mn = fminf(mn, wmin[w]);
    atomicMin(minp, __float_as_uint(fmaxf(mn, 0.0f)));
  }
}

// ---- fallback (only if ws too small): exact fp32 brute force ----
__global__ __launch_bounds__(64) void k_initmin(unsigned int* minp) {
  if (threadIdx.x == 0) *minp = 0x7f800000u;
}

__global__ __launch_bounds__(256) void k_brute(
    const float* __restrict__ pred, const float* __restrict__ cand,
    unsigned int* __restrict__ minp)
{
  __shared__ float yrow[DD];
  __shared__ float wm[4];
  const int c = blockIdx.x;
  for (int i = threadIdx.x; i < DD; i += 256) yrow[i] = cand[(size_t)c * DD + i];
  __syncthreads();
  float lmin = 3.4e38f;
  for (int p = threadIdx.x; p < P; p += 256) {
    const float* xp = pred + (size_t)p * DD;
    float s = 0.f;
    for (int k = 0; k < DD; ++k) { float d = xp[k] - yrow[k]; s = fmaf(d, d, s); }
    lmin = fminf(lmin, s);
  }
  #pragma unroll
  for (int off = 32; off; off >>= 1) lmin = fminf(lmin, __shfl_down(lmin, off, 64));
  if ((threadIdx.x & 63) == 0) wm[threadIdx.x >> 6] = lmin;
  __syncthreads();
  if (threadIdx.x == 0) {
    float mn = fminf(fminf(wm[0], wm[1]), fminf(wm[2], wm[3]));
    atomicMin(minp, __float_as_uint(fmaxf(mn, 0.0f)));
  }
}

__global__ __launch_bounds__(64) void k_finalize(const unsigned int* minp, float* out) {
  if (threadIdx.x == 0) out[0] = sqrtf(__uint_as_float(*minp));
}

extern "C" void kernel_launch(void* const* d_in, const int* in_sizes, int n_in,
                              void* d_out, int out_size, void* d_ws, size_t ws_size,
                              hipStream_t stream) {
  const float* pred = (const float*)d_in[0];
  const float* cand = (const float*)d_in[1];
  float* out = (float*)d_out;

  // ws layout: [0] min-bits | +16 floats: nx[2048] | ny[65536] | Abf bf16[2048*512] | Bpk bf16[65536*512]
  unsigned int* minp = (unsigned int*)d_ws;
  float* wsf = (float*)d_ws;
  float* nx = wsf + 16;
  float* ny = nx + P;
  unsigned short* Abf = (unsigned short*)(ny + R);
  unsigned short* Bpk = Abf + (size_t)P * DD;
  const size_t need = (size_t)(16 + P + R) * 4 + ((size_t)P * DD + (size_t)R * DD) * 2;

  if (ws_size >= need) {
    k_convert<<<2048, 256, 0, stream>>>(pred, cand, Abf, Bpk, nx, ny, minp);
    k_gemm_min<<<(P / BM) * (R / BN), 512, 0, stream>>>(Abf, Bpk, nx, ny, minp);
  } else {
    k_initmin<<<1, 64, 0, stream>>>(minp);
    k_brute<<<R, 256, 0, stream>>>(pred, cand, minp);
  }
  k_finalize<<<1, 64, 0, stream>>>(minp, out);
}

// Round 9
// 329.103 us; speedup vs baseline: 1.4624x; 1.4624x over previous
//
#include <hip/hip_runtime.h>
#include <stdint.h>

#define P 2048
#define R 65536
#define DD 512
#define BM 256
#define BN 256
#define BKB 128              // K-bytes per i8 tile (K=128 elements)
#define NTI 4                // i8 K-tiles (512/128)
#define BKH 64               // bf16 K-step for rescore
#define NTH 8
#define QS 24.0f             // i8 quant scale
#define MARGIN 10.0f         // d^2 selection margin (~12 sigma of i8 noise)

typedef __attribute__((ext_vector_type(8))) short short8;
typedef __attribute__((ext_vector_type(4))) float f32x4;
typedef __attribute__((ext_vector_type(4))) int i32x4;

__device__ inline unsigned short f2bf(float f) {
  unsigned int u = __float_as_uint(f);
  u += 0x7fffu + ((u >> 16) & 1u);   // round-to-nearest-even
  return (unsigned short)(u >> 16);
}

__device__ inline void gload_lds16(const void* g, void* l) {
  __builtin_amdgcn_global_load_lds(
      (const __attribute__((address_space(1))) unsigned int*)g,
      (__attribute__((address_space(3))) unsigned int*)l,
      16, 0, 0);
}

__device__ inline int q8(float v) {
  int q = __float2int_rn(v * QS);
  return q > 127 ? 127 : (q < -127 ? -127 : q);
}

// ---- kernel 1: fp32 -> int8 quant + fp32 row norms; one wave per row,
//      grid-stride. Aq/Bq row-major [rows][512] i8 (512 B rows). ----
__global__ __launch_bounds__(256) void k_convert(
    const float* __restrict__ pred, const float* __restrict__ cand,
    uint8_t* __restrict__ Aq, uint8_t* __restrict__ Bq,
    float* __restrict__ nx, float* __restrict__ ny,
    unsigned int* __restrict__ gminp, unsigned int* __restrict__ exactp)
{
  if (blockIdx.x == 0 && threadIdx.x == 0) { *gminp = 0x7f800000u; *exactp = 0x7f800000u; }
  const int lane = threadIdx.x & 63;
  const int wv   = (blockIdx.x << 2) | (threadIdx.x >> 6);
  const int nw   = gridDim.x << 2;
  for (int gw = wv; gw < P + R; gw += nw) {
    const float* src; uint8_t* dst; float* np;
    if (gw < P) { src = pred + (size_t)gw * DD; dst = Aq + (size_t)gw * DD; np = nx + gw; }
    else { int r = gw - P; src = cand + (size_t)r * DD; dst = Bq + (size_t)r * DD; np = ny + r; }
    const float4* s4 = ((const float4*)src) + lane * 2;
    float4 v0 = s4[0], v1 = s4[1];
    float ss = v0.x*v0.x + v0.y*v0.y + v0.z*v0.z + v0.w*v0.w
             + v1.x*v1.x + v1.y*v1.y + v1.z*v1.z + v1.w*v1.w;
    unsigned lo = (q8(v0.x) & 255) | ((q8(v0.y) & 255) << 8)
                | ((q8(v0.z) & 255) << 16) | ((q8(v0.w) & 255) << 24);
    unsigned hi = (q8(v1.x) & 255) | ((q8(v1.y) & 255) << 8)
                | ((q8(v1.z) & 255) << 16) | ((q8(v1.w) & 255) << 24);
    *(uint2*)(dst + (size_t)lane * 8) = make_uint2(lo, hi);
    #pragma unroll
    for (int off = 32; off; off >>= 1) ss += __shfl_down(ss, off, 64);
    if (lane == 0) *np = ss;
  }
}

// ---- kernel 2: int8 SCREENING GEMM (A·B^T), 256x256 tile, BKB=128 bytes
//      (K=128), 8 waves (2Mx4N), mfma_i32_16x16x64_i8 (K=64/instr, ~2x bf16
//      FLOP-rate, half the LDS/stage bytes), double-buffered LDS, round-1
//      skeleton (2 barriers/tile, counted vmcnt(8)), chunk-XOR swizzle whose
//      BYTE layout (128-B rows, 16-row fragment reads) is identical to the
//      measured-zero-conflict bf16 pattern. Epilogue: approx d~2 min per
//      tile -> tileMin[wg] (+ global atomicMin). Exactness comes from
//      k_rescore, selected via tileMin <= gmin + MARGIN.
//
// LDS per operand/buffer: [256][128] i8; 16B-chunks stored permuted:
// stored_chunk = data_chunk ^ (row & 7) via pre-swizzled global source.
// i8 fragments (byte-scaled analog of the verified bf16 16x16x32 mapping):
// A: row = lane&15, k = (lane>>4)*16 + e (16 bytes = 4 VGPR); per tile
// k-step ks: data chunk = ks*4 + quad. C/D layout dtype-independent:
// col = lane&15, row = quad*4 + reg.
__global__ __launch_bounds__(512, 2) void k_gemm_min(
    const uint8_t* __restrict__ Aq, const uint8_t* __restrict__ Bq,
    const float* __restrict__ nx, const float* __restrict__ ny,
    unsigned int* __restrict__ gminp, float* __restrict__ tileMin)
{
  __shared__ __align__(16) uint8_t As[2][BM * BKB];   // 2 x 32 KB
  __shared__ __align__(16) uint8_t Bs[2][BN * BKB];   // 2 x 32 KB
  __shared__ float wmin[8];

  const int tid  = threadIdx.x;
  const int wave = tid >> 6;
  const int lane = tid & 63;

  // XCD-aware bijective remap: 2048 blocks, 8 XCDs, 256 contiguous per XCD.
  const int raw = blockIdx.x;
  const int wg  = (raw & 7) * 256 + (raw >> 3);
  const int by  = wg & 7;
  const int bx  = wg >> 3;
  const int rowA0 = by * BM, rowB0 = bx * BN;
  const int wr = wave >> 2;           // 0..1 : M half (wave tile 128x64)
  const int wc = wave & 3;            // 0..3 : N quarter

  i32x4 zero = {0, 0, 0, 0};
  i32x4 acc[8][4];
  #pragma unroll
  for (int i = 0; i < 8; ++i)
    #pragma unroll
    for (int j = 0; j < 4; ++j) acc[i][j] = zero;

  // staging: per operand 32 wave-instrs (8 waves x t=0..3), each 8 rows x
  // 128 B (1 KB). lane L -> local row L>>3, stored chunk L&7, source data
  // chunk (L&7)^(L>>3).
  const int rloc = lane >> 3;
  const int cswz = (lane & 7) ^ rloc;
  const uint8_t* gA[4]; const uint8_t* gB[4];
  int lofs[4];
  #pragma unroll
  for (int t = 0; t < 4; ++t) {
    const int ii = wave * 4 + t;          // 0..31
    gA[t] = Aq + (size_t)(rowA0 + ii * 8 + rloc) * DD + cswz * 16;
    gB[t] = Bq + (size_t)(rowB0 + ii * 8 + rloc) * DD + cswz * 16;
    lofs[t] = ii * 1024 + lane * 16;      // bytes
  }

#define STAGE(s, kt) do { const int _k0 = (kt) * BKB;           \
    _Pragma("unroll")                                           \
    for (int _t = 0; _t < 4; ++_t) {                            \
      gload_lds16(gA[_t] + _k0, &As[s][lofs[_t]]);              \
      gload_lds16(gB[_t] + _k0, &Bs[s][lofs[_t]]);              \
    } } while (0)

  // fragment read geometry (bytes). A frag i: row wr*128+i*16+m; k-step ks:
  // data chunk ks*4+quad stored at chunk ^ (m&7).
  const int m = lane & 15, quad = lane >> 4, mb = m & 7;
  const int aRow0 = (wr * 128 + m) * BKB;
  const int bRow0 = (wc * 64  + m) * BKB;
  const int sw0 = ((quad    ) ^ mb) * 16;
  const int sw1 = ((quad + 4) ^ mb) * 16;

  STAGE(0, 0);

  for (int T = 0; T < NTI; ++T) {
    const int s = T & 1;
    if (T + 1 < NTI) {
      STAGE(s ^ 1, T + 1);
      asm volatile("s_waitcnt vmcnt(8)" ::: "memory");   // tile T landed
    } else {
      asm volatile("s_waitcnt vmcnt(0)" ::: "memory");
    }
    __builtin_amdgcn_s_barrier();

    // B fragments hoisted: 8 x b128 per tile
    i32x4 bfr[4][2];
    #pragma unroll
    for (int j = 0; j < 4; ++j) {
      const uint8_t* bp = &Bs[s][bRow0 + j * 16 * BKB];
      bfr[j][0] = *(const i32x4*)(bp + sw0);
      bfr[j][1] = *(const i32x4*)(bp + sw1);
    }
    #pragma unroll
    for (int mh = 0; mh < 2; ++mh) {
      i32x4 af[4][2];
      #pragma unroll
      for (int i = 0; i < 4; ++i) {
        const uint8_t* ap = &As[s][aRow0 + (mh * 4 + i) * 16 * BKB];
        af[i][0] = *(const i32x4*)(ap + sw0);
        af[i][1] = *(const i32x4*)(ap + sw1);
      }
      __builtin_amdgcn_s_setprio(1);
      #pragma unroll
      for (int i = 0; i < 4; ++i)
        #pragma unroll
        for (int j = 0; j < 4; ++j) {
          acc[mh*4+i][j] = __builtin_amdgcn_mfma_i32_16x16x64_i8(af[i][0], bfr[j][0], acc[mh*4+i][j], 0, 0, 0);
          acc[mh*4+i][j] = __builtin_amdgcn_mfma_i32_16x16x64_i8(af[i][1], bfr[j][1], acc[mh*4+i][j], 0, 0, 0);
        }
      __builtin_amdgcn_s_setprio(0);
    }
    __builtin_amdgcn_s_barrier();
  }
#undef STAGE

  // epilogue: d~2 = nx + ny - 2*dotq/QS^2 ; C/D: col=lane&15, row=quad*4+reg
  const float dsc = 2.0f / (QS * QS);
  float lmin = 3.4e38f;
  #pragma unroll
  for (int i = 0; i < 8; ++i) {
    const int mbase = rowA0 + wr * 128 + i * 16 + quad * 4;
    float4 nxv = *(const float4*)(nx + mbase);
    #pragma unroll
    for (int j = 0; j < 4; ++j) {
      const int n = rowB0 + wc * 64 + j * 16 + m;
      const float nyv = ny[n];
      i32x4 a = acc[i][j];
      lmin = fminf(lmin, nxv.x + nyv - dsc * (float)a[0]);
      lmin = fminf(lmin, nxv.y + nyv - dsc * (float)a[1]);
      lmin = fminf(lmin, nxv.z + nyv - dsc * (float)a[2]);
      lmin = fminf(lmin, nxv.w + nyv - dsc * (float)a[3]);
    }
  }
  #pragma unroll
  for (int off = 32; off; off >>= 1) lmin = fminf(lmin, __shfl_down(lmin, off, 64));
  if (lane == 0) wmin[wave] = lmin;
  __syncthreads();
  if (tid == 0) {
    float mn = wmin[0];
    #pragma unroll
    for (int w = 1; w < 8; ++w) mn = fminf(mn, wmin[w]);
    tileMin[wg] = mn;                                    // raw (signed ok)
    atomicMin(gminp, __float_as_uint(fmaxf(mn, 0.0f)));
  }
}

// ---- kernel 3: exact bf16-MFMA rescore of selected tiles from ORIGINAL
//      fp32 inputs (on-the-fly fp32->bf16 convert into LDS). Numerics =
//      the previously-passing full bf16 pipeline. ~2 blocks active. ----
__global__ __launch_bounds__(512) void k_rescore(
    const float* __restrict__ pred, const float* __restrict__ cand,
    const float* __restrict__ nx, const float* __restrict__ ny,
    const float* __restrict__ tileMin, const unsigned int* __restrict__ gminp,
    unsigned int* __restrict__ exactp)
{
  const int b  = blockIdx.x;          // tile id == screen's wg
  const int by = b & 7, bx = b >> 3;
  if (!(tileMin[b] <= __uint_as_float(*gminp) + MARGIN)) return;

  __shared__ __align__(16) unsigned short As[BM * BKH];   // 32 KB bf16
  __shared__ __align__(16) unsigned short Bs[BN * BKH];   // 32 KB
  __shared__ float wmin[8];

  const int tid  = threadIdx.x;
  const int wave = tid >> 6;
  const int lane = tid & 63;
  const int rowA0 = by * BM, rowB0 = bx * BN;
  const int wr = wave >> 2, wc = wave & 3;

  f32x4 zero = {0.f, 0.f, 0.f, 0.f};
  f32x4 acc[8][4];
  #pragma unroll
  for (int i = 0; i < 8; ++i)
    #pragma unroll
    for (int j = 0; j < 4; ++j) acc[i][j] = zero;

  // staging geometry (same [256][64]bf16, chunk-XOR ^ (row&7) layout)
  const int rloc = lane >> 3;
  const int dc   = (lane & 7) ^ rloc;       // data chunk for stored slot lane&7
  const int m = lane & 15, quad = lane >> 4, mb = m & 7;
  const int aRow0 = (wr * 128 + m) * BKH;
  const int bRow0 = (wc * 64  + m) * BKH;
  const int sw0 = ((quad    ) ^ mb) * 8;
  const int sw1 = ((quad + 4) ^ mb) * 8;

  for (int kt = 0; kt < NTH; ++kt) {
    // load fp32 + convert to bf16 in regs
    uint4 apk[4], bpk[4];
    #pragma unroll
    for (int t = 0; t < 4; ++t) {
      const int ii = wave * 4 + t;
      const float* pa = pred + (size_t)(rowA0 + ii * 8 + rloc) * DD + kt * BKH + dc * 8;
      const float* pb = cand + (size_t)(rowB0 + ii * 8 + rloc) * DD + kt * BKH + dc * 8;
      float4 a0 = *(const float4*)pa, a1 = *(const float4*)(pa + 4);
      float4 b0 = *(const float4*)pb, b1 = *(const float4*)(pb + 4);
      union { unsigned short h[8]; uint4 v; } u;
      u.h[0]=f2bf(a0.x); u.h[1]=f2bf(a0.y); u.h[2]=f2bf(a0.z); u.h[3]=f2bf(a0.w);
      u.h[4]=f2bf(a1.x); u.h[5]=f2bf(a1.y); u.h[6]=f2bf(a1.z); u.h[7]=f2bf(a1.w);
      apk[t] = u.v;
      u.h[0]=f2bf(b0.x); u.h[1]=f2bf(b0.y); u.h[2]=f2bf(b0.z); u.h[3]=f2bf(b0.w);
      u.h[4]=f2bf(b1.x); u.h[5]=f2bf(b1.y); u.h[6]=f2bf(b1.z); u.h[7]=f2bf(b1.w);
      bpk[t] = u.v;
    }
    __syncthreads();                       // previous tile's reads done
    #pragma unroll
    for (int t = 0; t < 4; ++t) {
      const int ii = wave * 4 + t;
      *(uint4*)(&As[ii * 512 + lane * 8]) = apk[t];
      *(uint4*)(&Bs[ii * 512 + lane * 8]) = bpk[t];
    }
    __syncthreads();                       // writes visible

    short8 bfr[4][2];
    #pragma unroll
    for (int j = 0; j < 4; ++j) {
      const unsigned short* bp = Bs + bRow0 + j * 16 * BKH;
      bfr[j][0] = *(const short8*)(bp + sw0);
      bfr[j][1] = *(const short8*)(bp + sw1);
    }
    #pragma unroll
    for (int mh = 0; mh < 2; ++mh) {
      short8 af[4][2];
      #pragma unroll
      for (int i = 0; i < 4; ++i) {
        const unsigned short* ap = As + aRow0 + (mh * 4 + i) * 16 * BKH;
        af[i][0] = *(const short8*)(ap + sw0);
        af[i][1] = *(const short8*)(ap + sw1);
      }
      #pragma unroll
      for (int i = 0; i < 4; ++i)
        #pragma unroll
        for (int j = 0; j < 4; ++j) {
          acc[mh*4+i][j] = __builtin_amdgcn_mfma_f32_16x16x32_bf16(af[i][0], bfr[j][0], acc[mh*4+i][j], 0, 0, 0);
          acc[mh*4+i][j] = __builtin_amdgcn_mfma_f32_16x16x32_bf16(af[i][1], bfr[j][1], acc[mh*4+i][j], 0, 0, 0);
        }
    }
  }

  float lmin = 3.4e38f;
  #pragma unroll
  for (int i = 0; i < 8; ++i) {
    const int mbase = rowA0 + wr * 128 + i * 16 + quad * 4;
    float4 nxv = *(const float4*)(nx + mbase);
    #pragma unroll
    for (int j = 0; j < 4; ++j) {
      const int n = rowB0 + wc * 64 + j * 16 + m;
      const float nyv = ny[n];
      f32x4 a = acc[i][j];
      lmin = fminf(lmin, nxv.x + nyv - 2.0f * a[0]);
      lmin = fminf(lmin, nxv.y + nyv - 2.0f * a[1]);
      lmin = fminf(lmin, nxv.z + nyv - 2.0f * a[2]);
      lmin = fminf(lmin, nxv.w + nyv - 2.0f * a[3]);
    }
  }
  #pragma unroll
  for (int off = 32; off; off >>= 1) lmin = fminf(lmin, __shfl_down(lmin, off, 64));
  if (lane == 0) wmin[wave] = lmin;
  __syncthreads();
  if (tid == 0) {
    float mn = wmin[0];
    #pragma unroll
    for (int w = 1; w < 8; ++w) mn = fminf(mn, wmin[w]);
    atomicMin(exactp, __float_as_uint(fmaxf(mn, 0.0f)));
  }
}

// ---- fallback (only if ws too small): exact fp32 brute force ----
__global__ __launch_bounds__(64) void k_initmin(unsigned int* minp) {
  if (threadIdx.x == 0) *minp = 0x7f800000u;
}

__global__ __launch_bounds__(256) void k_brute(
    const float* __restrict__ pred, const float* __restrict__ cand,
    unsigned int* __restrict__ minp)
{
  __shared__ float yrow[DD];
  __shared__ float wm[4];
  const int c = blockIdx.x;
  for (int i = threadIdx.x; i < DD; i += 256) yrow[i] = cand[(size_t)c * DD + i];
  __syncthreads();
  float lmin = 3.4e38f;
  for (int p = threadIdx.x; p < P; p += 256) {
    const float* xp = pred + (size_t)p * DD;
    float s = 0.f;
    for (int k = 0; k < DD; ++k) { float d = xp[k] - yrow[k]; s = fmaf(d, d, s); }
    lmin = fminf(lmin, s);
  }
  #pragma unroll
  for (int off = 32; off; off >>= 1) lmin = fminf(lmin, __shfl_down(lmin, off, 64));
  if ((threadIdx.x & 63) == 0) wm[threadIdx.x >> 6] = lmin;
  __syncthreads();
  if (threadIdx.x == 0) {
    float mn = fminf(fminf(wm[0], wm[1]), fminf(wm[2], wm[3]));
    atomicMin(minp, __float_as_uint(fmaxf(mn, 0.0f)));
  }
}

__global__ __launch_bounds__(64) void k_finalize(const unsigned int* minp, float* out) {
  if (threadIdx.x == 0) out[0] = sqrtf(__uint_as_float(*minp));
}

extern "C" void kernel_launch(void* const* d_in, const int* in_sizes, int n_in,
                              void* d_out, int out_size, void* d_ws, size_t ws_size,
                              hipStream_t stream) {
  const float* pred = (const float*)d_in[0];
  const float* cand = (const float*)d_in[1];
  float* out = (float*)d_out;

  // ws: [0] gmin | [1] exact | +16f: nx[2048] | ny[65536] | tileMin[2048] |
  //     Aq i8[2048*512] | Bq i8[65536*512]
  unsigned int* gminp  = (unsigned int*)d_ws;
  unsigned int* exactp = gminp + 1;
  float* wsf = (float*)d_ws;
  float* nx = wsf + 16;
  float* ny = nx + P;
  float* tileMin = ny + R;
  uint8_t* Aq = (uint8_t*)(tileMin + 2048);
  uint8_t* Bq = Aq + (size_t)P * DD;
  const size_t need = (size_t)(16 + P + R + 2048) * 4 + (size_t)(P + R) * DD;

  if (ws_size >= need) {
    k_convert<<<2048, 256, 0, stream>>>(pred, cand, Aq, Bq, nx, ny, gminp, exactp);
    k_gemm_min<<<(P / BM) * (R / BN), 512, 0, stream>>>(Aq, Bq, nx, ny, gminp, tileMin);
    k_rescore<<<(P / BM) * (R / BN), 512, 0, stream>>>(pred, cand, nx, ny, tileMin, gminp, exactp);
    k_finalize<<<1, 64, 0, stream>>>(exactp, out);
  } else {
    k_initmin<<<1, 64, 0, stream>>>(gminp);
    k_brute<<<R, 256, 0, stream>>>(pred, cand, gminp);
    k_finalize<<<1, 64, 0, stream>>>(gminp, out);
  }
}